// Round 1
// baseline (319.108 us; speedup 1.0000x reference)
//
#include <hip/hip_runtime.h>
#include <stdint.h>

#define NPIX 9216   // 96*96
#define NIMG 32

// ---------- JAX threefry2x32 (20 rounds), bit-exact ----------
__device__ __forceinline__ uint32_t rotl32(uint32_t x, int d){ return (x<<d)|(x>>(32-d)); }

__device__ __forceinline__ void threefry(uint32_t k0, uint32_t k1, uint32_t x0, uint32_t x1,
                                         uint32_t &o0, uint32_t &o1){
  uint32_t ks2 = k0 ^ k1 ^ 0x1BD11BDAu;
  x0 += k0; x1 += k1;
  x0+=x1; x1=rotl32(x1,13); x1^=x0;
  x0+=x1; x1=rotl32(x1,15); x1^=x0;
  x0+=x1; x1=rotl32(x1,26); x1^=x0;
  x0+=x1; x1=rotl32(x1,6);  x1^=x0;
  x0+=k1; x1+=ks2+1u;
  x0+=x1; x1=rotl32(x1,17); x1^=x0;
  x0+=x1; x1=rotl32(x1,29); x1^=x0;
  x0+=x1; x1=rotl32(x1,16); x1^=x0;
  x0+=x1; x1=rotl32(x1,24); x1^=x0;
  x0+=ks2; x1+=k0+2u;
  x0+=x1; x1=rotl32(x1,13); x1^=x0;
  x0+=x1; x1=rotl32(x1,15); x1^=x0;
  x0+=x1; x1=rotl32(x1,26); x1^=x0;
  x0+=x1; x1=rotl32(x1,6);  x1^=x0;
  x0+=k0; x1+=k1+3u;
  x0+=x1; x1=rotl32(x1,17); x1^=x0;
  x0+=x1; x1=rotl32(x1,29); x1^=x0;
  x0+=x1; x1=rotl32(x1,16); x1^=x0;
  x0+=x1; x1=rotl32(x1,24); x1^=x0;
  x0+=k1; x1+=ks2+4u;
  x0+=x1; x1=rotl32(x1,13); x1^=x0;
  x0+=x1; x1=rotl32(x1,15); x1^=x0;
  x0+=x1; x1=rotl32(x1,26); x1^=x0;
  x0+=x1; x1=rotl32(x1,6);  x1^=x0;
  x0+=ks2; x1+=k0+5u;
  o0=x0; o1=x1;
}

__device__ __forceinline__ float u01(uint32_t bits){
  // JAX uniform: bitcast(bits>>9 | 0x3f800000) - 1.0
  return __uint_as_float((bits >> 9) | 0x3f800000u) - 1.0f;
}

__device__ __forceinline__ float clip01_div255(float x){
  return fminf(fmaxf(x/255.0f, 0.0f), 1.0f);
}

// ---------- Kernel A: per-image channel max + fg mask ----------
__global__ __launch_bounds__(256) void kmax_mask(const float* __restrict__ in,
                                                unsigned char* __restrict__ mask){
#pragma clang fp contract(off)
  int img = blockIdx.x;
  const float* p = in + (size_t)img*NPIX*3;
  __shared__ float red[3][256];
  float m0=0.f,m1=0.f,m2=0.f;
  for(int i=threadIdx.x;i<NPIX;i+=256){
    m0=fmaxf(m0, clip01_div255(p[i*3+0]));
    m1=fmaxf(m1, clip01_div255(p[i*3+1]));
    m2=fmaxf(m2, clip01_div255(p[i*3+2]));
  }
  red[0][threadIdx.x]=m0; red[1][threadIdx.x]=m1; red[2][threadIdx.x]=m2;
  __syncthreads();
  for(int s=128;s>0;s>>=1){
    if(threadIdx.x<(unsigned)s){
      red[0][threadIdx.x]=fmaxf(red[0][threadIdx.x],red[0][threadIdx.x+s]);
      red[1][threadIdx.x]=fmaxf(red[1][threadIdx.x],red[1][threadIdx.x+s]);
      red[2][threadIdx.x]=fmaxf(red[2][threadIdx.x],red[2][threadIdx.x+s]);
    }
    __syncthreads();
  }
  float c0=red[0][0], c1=red[1][0], c2=red[2][0];
  unsigned char* mk = mask + (size_t)img*NPIX;
  for(int i=threadIdx.x;i<NPIX;i+=256){
    float a=clip01_div255(p[i*3+0])/c0;
    float b=clip01_div255(p[i*3+1])/c1;
    float c=clip01_div255(p[i*3+2])/c2;
    // cleaned>0 <=> img_norm>0 && img_norm<0.6f  (0.6 weak-typed -> f32)
    bool fg = (a>0.f && a<0.6f) || (b>0.f && b<0.6f) || (c>0.f && c<0.6f);
    mk[i] = fg?1:0;
  }
}

// ---------- Kernel B: threefry sampling + stable top-50 selection ----------
__global__ __launch_bounds__(256) void ksample(const unsigned char* __restrict__ mask,
                                               int* __restrict__ train_idx){
  int img = blockIdx.x >> 1;
  int cls = blockIdx.x & 1;     // 0 = fg, 1 = bg
  int tid = threadIdx.x;
  __shared__ float score[NPIX];
  __shared__ float rv[4];
  __shared__ int   ri[4];

  // partitionable threefry path (JAX >= 0.4.30 default):
  //   keys = split(key(42), 32): key_b = threefry((0,42),(0,b)) full pair
  //   (k_fg,k_bg) = split(key_b): threefry(key_b,(0,0)) / threefry(key_b,(0,1))
  uint32_t ik0, ik1; threefry(0u, 42u, 0u, (uint32_t)img, ik0, ik1);
  uint32_t s0, s1;   threefry(ik0, ik1, 0u, (uint32_t)cls, s0, s1);

  const unsigned char* mk = mask + (size_t)img*NPIX;
  for(int i=tid;i<NPIX;i+=256){
    uint32_t b1,b2; threefry(s0, s1, 0u, (uint32_t)i, b1, b2);
    float u = u01(b1 ^ b2);   // 32-bit random_bits = o0 ^ o1 (partitionable)
    bool valid = (cls==0) ? (mk[i]!=0) : (mk[i]==0);
    score[i] = valid ? u : -1.0f;
  }
  __syncthreads();

  int* oidx = train_idx + img*100 + cls*50;
  int lane = tid & 63, wv = tid >> 6;
  for(int k=0;k<50;k++){
    float bv=-3.f; int bi=0;
    for(int i=tid;i<NPIX;i+=256){
      float v=score[i];
      if(v>bv){bv=v;bi=i;}      // increasing i: tie keeps earlier index
    }
    for(int off=32;off>0;off>>=1){
      float ov=__shfl_down(bv,off); int oi=__shfl_down(bi,off);
      if(ov>bv || (ov==bv && oi<bi)){bv=ov;bi=oi;}
    }
    if(lane==0){rv[wv]=bv;ri[wv]=bi;}
    __syncthreads();
    if(tid==0){
      float fb=rv[0]; int fi=ri[0];
      for(int w=1;w<4;w++){ if(rv[w]>fb || (rv[w]==fb && ri[w]<fi)){fb=rv[w];fi=ri[w];} }
      oidx[k]=fi; score[fi]=-2.0f;
    }
    __syncthreads();
  }
}

// ---------- Kernel C: train features, mean/std (sequential f32), standardize ----------
__global__ __launch_bounds__(128) void kstats(const float* __restrict__ in,
                                              const int* __restrict__ train_idx,
                                              float* __restrict__ train_s,
                                              float* __restrict__ meanstd){
#pragma clang fp contract(off)
  int img=blockIdx.x; int t=threadIdx.x;
  __shared__ float feat[100][5];
  __shared__ float mv[5], sv[5];
  if(t<100){
    int p = train_idx[img*100+t];
    int i=p/96, j=p-i*96;
    const float* px = in + ((size_t)img*NPIX + p)*3;
    for(int c=0;c<3;c++){
      float ip=clip01_div255(px[c]);
      feat[t][c]=ip/255.0f;             // img01/255 (second divide per reference)
    }
    feat[t][3]=((float)i/96.0f)*100.0f;
    feat[t][4]=((float)j/96.0f)*100.0f;
  }
  __syncthreads();
  if(t<5){
    float s=0.f;
    for(int r=0;r<100;r++) s=s+feat[r][t];
    float m=s/100.0f;
    mv[t]=m;
    float v=0.f;
    for(int r=0;r<100;r++){ float d=feat[r][t]-m; float q=d*d; v=v+q; }
    sv[t]=sqrtf(v/100.0f);
  }
  __syncthreads();
  if(t<100){
    for(int k=0;k<5;k++) train_s[(img*100+t)*5+k]=(feat[t][k]-mv[k])/sv[k];
  }
  if(t<5)       meanstd[img*10+t]=mv[t];
  else if(t<10) meanstd[img*10+t]=sv[t-5];
}

// ---------- Kernel D: brute-force 5-NN (stable ties), segment, mask output ----------
__global__ __launch_bounds__(256) void kknn(const float* __restrict__ in,
                                            const float* __restrict__ train_s,
                                            const float* __restrict__ meanstd,
                                            float* __restrict__ out){
#pragma clang fp contract(off)
  int img   = blockIdx.x / 36;
  int chunk = blockIdx.x % 36;
  int tid=threadIdx.x;
  __shared__ float ts[100][5];
  __shared__ float mv[5], sv[5];
  if(tid<100){ for(int k=0;k<5;k++) ts[tid][k]=train_s[(img*100+tid)*5+k]; }
  if(tid>=128 && tid<133) mv[tid-128]=meanstd[img*10+(tid-128)];
  if(tid>=160 && tid<165) sv[tid-160]=meanstd[img*10+5+(tid-160)];
  __syncthreads();

  int p = chunk*256+tid;
  int i=p/96, j=p-i*96;
  const float* px = in + ((size_t)img*NPIX+p)*3;
  float ip0=clip01_div255(px[0]);
  float ip1=clip01_div255(px[1]);
  float ip2=clip01_div255(px[2]);
  float f[5]={ip0/255.0f, ip1/255.0f, ip2/255.0f,
              ((float)i/96.0f)*100.0f, ((float)j/96.0f)*100.0f};
  float tt[5];
  for(int k=0;k<5;k++) tt[k]=(f[k]-mv[k])/sv[k];

  float bd[5]={1e30f,1e30f,1e30f,1e30f,1e30f};
  int   bix[5]={1000,1000,1000,1000,1000};
  for(int jn=0;jn<100;jn++){
    float d2=0.f;
    for(int k=0;k<5;k++){ float df=tt[k]-ts[jn][k]; float q=df*df; d2=d2+q; }
    float d=sqrtf(d2);
    if(d<bd[4]){                      // tie at boundary: existing (lower idx) stays
      int pos=4;
      while(pos>0 && bd[pos-1]>d){ bd[pos]=bd[pos-1]; bix[pos]=bix[pos-1]; pos--; }
      bd[pos]=d; bix[pos]=jn;
    }
  }
  int cnt=(bix[0]<50)+(bix[1]<50)+(bix[2]<50)+(bix[3]<50)+(bix[4]<50);
  bool seg = cnt>=2;                  // mean>=0.3  <=>  count>=2
  float* po = out + ((size_t)img*NPIX+p)*3;
  po[0]=seg?ip0:0.f; po[1]=seg?ip1:0.f; po[2]=seg?ip2:0.f;
}

extern "C" void kernel_launch(void* const* d_in, const int* in_sizes, int n_in,
                              void* d_out, int out_size, void* d_ws, size_t ws_size,
                              hipStream_t stream) {
  const float* in = (const float*)d_in[0];
  float* out = (float*)d_out;
  // ws layout
  unsigned char* mask = (unsigned char*)d_ws;                    // 32*9216 = 294912 B
  int*   tidx    = (int*)  ((char*)d_ws + 294912);               // 32*100*4 = 12800 B
  float* train_s = (float*)((char*)d_ws + 307712);               // 32*500*4 = 64000 B
  float* meanstd = (float*)((char*)d_ws + 371712);               // 32*10*4  = 1280 B

  kmax_mask<<<NIMG, 256, 0, stream>>>(in, mask);
  ksample  <<<NIMG*2, 256, 0, stream>>>(mask, tidx);
  kstats   <<<NIMG, 128, 0, stream>>>(in, tidx, train_s, meanstd);
  kknn     <<<NIMG*36, 256, 0, stream>>>(in, train_s, meanstd, out);
}

// Round 2
// 142.158 us; speedup vs baseline: 2.2447x; 2.2447x over previous
//
#include <hip/hip_runtime.h>
#include <stdint.h>

#define NPIX 9216   // 96*96
#define NIMG 32

// ---------- JAX threefry2x32 (20 rounds), bit-exact ----------
__device__ __forceinline__ uint32_t rotl32(uint32_t x, int d){ return (x<<d)|(x>>(32-d)); }

__device__ __forceinline__ void threefry(uint32_t k0, uint32_t k1, uint32_t x0, uint32_t x1,
                                         uint32_t &o0, uint32_t &o1){
  uint32_t ks2 = k0 ^ k1 ^ 0x1BD11BDAu;
  x0 += k0; x1 += k1;
  x0+=x1; x1=rotl32(x1,13); x1^=x0;
  x0+=x1; x1=rotl32(x1,15); x1^=x0;
  x0+=x1; x1=rotl32(x1,26); x1^=x0;
  x0+=x1; x1=rotl32(x1,6);  x1^=x0;
  x0+=k1; x1+=ks2+1u;
  x0+=x1; x1=rotl32(x1,17); x1^=x0;
  x0+=x1; x1=rotl32(x1,29); x1^=x0;
  x0+=x1; x1=rotl32(x1,16); x1^=x0;
  x0+=x1; x1=rotl32(x1,24); x1^=x0;
  x0+=ks2; x1+=k0+2u;
  x0+=x1; x1=rotl32(x1,13); x1^=x0;
  x0+=x1; x1=rotl32(x1,15); x1^=x0;
  x0+=x1; x1=rotl32(x1,26); x1^=x0;
  x0+=x1; x1=rotl32(x1,6);  x1^=x0;
  x0+=k0; x1+=k1+3u;
  x0+=x1; x1=rotl32(x1,17); x1^=x0;
  x0+=x1; x1=rotl32(x1,29); x1^=x0;
  x0+=x1; x1=rotl32(x1,16); x1^=x0;
  x0+=x1; x1=rotl32(x1,24); x1^=x0;
  x0+=k1; x1+=ks2+4u;
  x0+=x1; x1=rotl32(x1,13); x1^=x0;
  x0+=x1; x1=rotl32(x1,15); x1^=x0;
  x0+=x1; x1=rotl32(x1,26); x1^=x0;
  x0+=x1; x1=rotl32(x1,6);  x1^=x0;
  x0+=ks2; x1+=k0+5u;
  o0=x0; o1=x1;
}

__device__ __forceinline__ float clip01_div255(float x){
  return fminf(fmaxf(x/255.0f, 0.0f), 1.0f);
}

// ---------- Kernel A: per-image channel max via atomicMax (exact) ----------
// 6 blocks per image, each handles 1536 pixels = 4608 contiguous dwords.
__global__ __launch_bounds__(256) void kmax(const float* __restrict__ in,
                                            uint32_t* __restrict__ cmax){
  int img  = blockIdx.x / 6;
  int part = blockIdx.x % 6;
  int tid  = threadIdx.x;
  const float* base = in + (size_t)img*NPIX*3 + (size_t)part*1536*3;
  float m0=0.f, m1=0.f, m2=0.f;
#pragma unroll
  for(int k=0;k<18;k++){
    int g = k*256 + tid;
    float v = clip01_div255(base[g]);
    int c = g % 3;
    m0 = (c==0) ? fmaxf(m0,v) : m0;
    m1 = (c==1) ? fmaxf(m1,v) : m1;
    m2 = (c==2) ? fmaxf(m2,v) : m2;
  }
  // reduce within wave, then across 4 waves via LDS
  for(int off=32; off>0; off>>=1){
    m0 = fmaxf(m0, __shfl_down(m0,off));
    m1 = fmaxf(m1, __shfl_down(m1,off));
    m2 = fmaxf(m2, __shfl_down(m2,off));
  }
  __shared__ float r[3][4];
  int lane = tid & 63, wv = tid >> 6;
  if(lane==0){ r[0][wv]=m0; r[1][wv]=m1; r[2][wv]=m2; }
  __syncthreads();
  if(tid==0){
    float a=fmaxf(fmaxf(r[0][0],r[0][1]),fmaxf(r[0][2],r[0][3]));
    float b=fmaxf(fmaxf(r[1][0],r[1][1]),fmaxf(r[1][2],r[1][3]));
    float c=fmaxf(fmaxf(r[2][0],r[2][1]),fmaxf(r[2][2],r[2][3]));
    // positive floats: uint bit pattern is order-isomorphic
    atomicMax(&cmax[img*3+0], __float_as_uint(a));
    atomicMax(&cmax[img*3+1], __float_as_uint(b));
    atomicMax(&cmax[img*3+2], __float_as_uint(c));
  }
}

// ---------- Kernel B: threefry + histogram-based stable top-50 ----------
__global__ __launch_bounds__(256) void ksample(const float* __restrict__ in,
                                               const uint32_t* __restrict__ cmax,
                                               int* __restrict__ train_idx){
  int img = blockIdx.x >> 1;
  int cls = blockIdx.x & 1;     // 0 = fg, 1 = bg
  int tid = threadIdx.x;

  __shared__ uint32_t score[NPIX];   // vv = (bits>>9)+1 if valid else 0   (36 KB)
  __shared__ int hist[129];
  __shared__ uint64_t cand[1024];
  __shared__ int ncand, bbin;

  if(tid<129) hist[tid]=0;
  if(tid==0)  ncand=0;
  __syncthreads();

  // partitionable threefry path (verified bit-exact in round 1):
  uint32_t ik0, ik1; threefry(0u, 42u, 0u, (uint32_t)img, ik0, ik1);
  uint32_t s0, s1;   threefry(ik0, ik1, 0u, (uint32_t)cls, s0, s1);

  float c0 = __uint_as_float(cmax[img*3+0]);
  float c1 = __uint_as_float(cmax[img*3+1]);
  float c2 = __uint_as_float(cmax[img*3+2]);

  const float* p = in + (size_t)img*NPIX*3;
  for(int i=tid;i<NPIX;i+=256){
    float a=clip01_div255(p[i*3+0])/c0;
    float b=clip01_div255(p[i*3+1])/c1;
    float c=clip01_div255(p[i*3+2])/c2;
    bool fg = (a>0.f && a<0.6f) || (b>0.f && b<0.6f) || (c>0.f && c<0.6f);
    bool valid = (cls==0) ? fg : !fg;
    uint32_t b1,b2; threefry(s0, s1, 0u, (uint32_t)i, b1, b2);
    uint32_t vv = valid ? ((b1 ^ b2) >> 9) + 1u : 0u;   // monotone in uniform; 0 = invalid(-1.0)
    score[i] = vv;
    atomicAdd(&hist[vv>>16], 1);
  }
  __syncthreads();

  if(tid==0){
    int acc=0, b=128;
    for(; b>=0; b--){ acc += hist[b]; if(acc>=50) break; }
    bbin = b;                       // cumulative count from top reaches >=50 at bin b
  }
  __syncthreads();

  int bb = bbin;
  for(int i=tid;i<NPIX;i+=256){
    uint32_t vv = score[i];
    if((int)(vv>>16) >= bb){
      int pos = atomicAdd(&ncand,1);
      if(pos < 1024)
        cand[pos] = ((uint64_t)vv << 14) | (uint64_t)(16383 - i);  // higher key = earlier
    }
  }
  __syncthreads();

  int m = ncand; if(m>1024) m=1024;
  int* oidx = train_idx + img*100 + cls*50;
  for(int c=tid;c<m;c+=256){
    uint64_t k = cand[c];
    int r = 0;
    for(int j=0;j<m;j++) r += (cand[j] > k);
    if(r < 50) oidx[r] = 16383 - (int)(k & 16383u);
  }
}

// ---------- Kernel C: train features, mean/std (sequential f32), standardize ----------
__global__ __launch_bounds__(128) void kstats(const float* __restrict__ in,
                                              const int* __restrict__ train_idx,
                                              float* __restrict__ train_s,
                                              float* __restrict__ meanstd){
#pragma clang fp contract(off)
  int img=blockIdx.x; int t=threadIdx.x;
  __shared__ float feat[100][5];
  __shared__ float mv[5], sv[5];
  if(t<100){
    int p = train_idx[img*100+t];
    int i=p/96, j=p-i*96;
    const float* px = in + ((size_t)img*NPIX + p)*3;
    for(int c=0;c<3;c++){
      float ip=clip01_div255(px[c]);
      feat[t][c]=ip/255.0f;
    }
    feat[t][3]=((float)i/96.0f)*100.0f;
    feat[t][4]=((float)j/96.0f)*100.0f;
  }
  __syncthreads();
  if(t<5){
    float s=0.f;
    for(int r=0;r<100;r++) s=s+feat[r][t];
    float m=s/100.0f;
    mv[t]=m;
    float v=0.f;
    for(int r=0;r<100;r++){ float d=feat[r][t]-m; float q=d*d; v=v+q; }
    sv[t]=sqrtf(v/100.0f);
  }
  __syncthreads();
  if(t<100){
    for(int k=0;k<5;k++) train_s[(img*100+t)*5+k]=(feat[t][k]-mv[k])/sv[k];
  }
  if(t<5)       meanstd[img*10+t]=mv[t];
  else if(t<10) meanstd[img*10+t]=sv[t-5];
}

// ---------- Kernel D: brute-force 5-NN, ILP-4, branchless insert, LDS-staged I/O ----
__global__ __launch_bounds__(256) void kknn(const float* __restrict__ in,
                                            const float* __restrict__ train_s,
                                            const float* __restrict__ meanstd,
                                            float* __restrict__ out){
#pragma clang fp contract(off)
  int img   = blockIdx.x / 36;
  int chunk = blockIdx.x % 36;
  int tid   = threadIdx.x;
  __shared__ float ts[100][5];
  __shared__ float mv[5], sv[5];
  __shared__ float pix[768];
  if(tid<100){ for(int k=0;k<5;k++) ts[tid][k]=train_s[(img*100+tid)*5+k]; }
  if(tid>=128 && tid<133) mv[tid-128]=meanstd[img*10+(tid-128)];
  if(tid>=160 && tid<165) sv[tid-160]=meanstd[img*10+5+(tid-160)];
  // coalesced load of this chunk's 768 contiguous dwords
  const float* cb = in + ((size_t)img*NPIX + (size_t)chunk*256)*3;
  pix[tid]     = cb[tid];
  pix[tid+256] = cb[tid+256];
  pix[tid+512] = cb[tid+512];
  __syncthreads();

  int p = chunk*256+tid;
  int i=p/96, j=p-i*96;
  float ip0=clip01_div255(pix[tid*3+0]);
  float ip1=clip01_div255(pix[tid*3+1]);
  float ip2=clip01_div255(pix[tid*3+2]);
  float tt[5];
  {
    float f[5]={ip0/255.0f, ip1/255.0f, ip2/255.0f,
                ((float)i/96.0f)*100.0f, ((float)j/96.0f)*100.0f};
#pragma unroll
    for(int k=0;k<5;k++) tt[k]=(f[k]-mv[k])/sv[k];
  }

  float bd0=1e30f,bd1=1e30f,bd2=1e30f,bd3=1e30f,bd4=1e30f;
  int   bx0=1000,bx1=1000,bx2=1000,bx3=1000,bx4=1000;
#pragma unroll 5
  for(int jn=0;jn<100;jn+=4){
    float dd[4];
#pragma unroll
    for(int u=0;u<4;u++){
      float s=0.f;
#pragma unroll
      for(int k=0;k<5;k++){ float df=tt[k]-ts[jn+u][k]; float q=df*df; s=s+q; }
      dd[u]=sqrtf(s);
    }
#pragma unroll
    for(int u=0;u<4;u++){
      float d=dd[u]; int id=jn+u;
      // strict-< insert: on tie, existing (earlier/lower train index) stays -> stable top_k
      bool l4=d<bd4, l3=d<bd3, l2=d<bd2, l1=d<bd1, l0=d<bd0;
      bd4 = l4 ? (l3?bd3:d) : bd4;   bx4 = l4 ? (l3?bx3:id) : bx4;
      bd3 = l3 ? (l2?bd2:d) : bd3;   bx3 = l3 ? (l2?bx2:id) : bx3;
      bd2 = l2 ? (l1?bd1:d) : bd2;   bx2 = l2 ? (l1?bx1:id) : bx2;
      bd1 = l1 ? (l0?bd0:d) : bd1;   bx1 = l1 ? (l0?bx0:id) : bx1;
      bd0 = l0 ? d : bd0;            bx0 = l0 ? id : bx0;
    }
  }
  int cnt=(bx0<50)+(bx1<50)+(bx2<50)+(bx3<50)+(bx4<50);
  bool seg = cnt>=2;                  // mean>=0.3  <=>  count>=2
  __syncthreads();                    // pix[] reload fence
  pix[tid*3+0]=seg?ip0:0.f;
  pix[tid*3+1]=seg?ip1:0.f;
  pix[tid*3+2]=seg?ip2:0.f;
  __syncthreads();
  float* ob = out + ((size_t)img*NPIX + (size_t)chunk*256)*3;
  ob[tid]     = pix[tid];
  ob[tid+256] = pix[tid+256];
  ob[tid+512] = pix[tid+512];
}

extern "C" void kernel_launch(void* const* d_in, const int* in_sizes, int n_in,
                              void* d_out, int out_size, void* d_ws, size_t ws_size,
                              hipStream_t stream) {
  const float* in = (const float*)d_in[0];
  float* out = (float*)d_out;
  // ws layout
  uint32_t* cmax  = (uint32_t*)d_ws;                         // 32*3*4 = 384 B
  int*   tidx     = (int*)  ((char*)d_ws + 384);             // 32*100*4 = 12800 B
  float* train_s  = (float*)((char*)d_ws + 13184);           // 32*500*4 = 64000 B
  float* meanstd  = (float*)((char*)d_ws + 77184);           // 32*10*4  = 1280 B

  hipMemsetAsync(d_ws, 0, 384, stream);                      // zero cmax
  kmax   <<<NIMG*6,  256, 0, stream>>>(in, cmax);
  ksample<<<NIMG*2,  256, 0, stream>>>(in, cmax, tidx);
  kstats <<<NIMG,    128, 0, stream>>>(in, tidx, train_s, meanstd);
  kknn   <<<NIMG*36, 256, 0, stream>>>(in, train_s, meanstd, out);
}